// Round 2
// baseline (376.874 us; speedup 1.0000x reference)
//
#include <hip/hip_runtime.h>

// PolyPoolerTextLenSensitive — MI355X (gfx950)
//
// Inputs (setup_inputs order):
//   d_in[0] feat0  (2,256,200,336) f32
//   d_in[1] feat1  (2,256,100,168) f32
//   d_in[2] feat2  (2,256, 50, 84) f32
//   d_in[3] feat3  (2,256, 25, 42) f32
//   d_in[4] polys  (256,14,2)      f32
//   d_in[5] img_ids(256,)          i32
//   d_in[6] lens   (256,)          i32
// Output: out0 (256,256,8,32) then out1 (256,256,8,64), f32, concat flat.
//
// R2: latency-bound fix — explicit channel-loop unroll for ~32 loads in
// flight per wave (R1 had VGPR=28 -> ~4). wp=64 path: thread owns two
// ADJACENT positions -> float2 stores + tighter gather locality.

#define NBOX 256
#define NCH  256
#define HP   8
#define CCHUNK 32
#define OUT0_ELEMS ((size_t)NBOX * NCH * HP * 32)

struct Geo {
    int   o[4];
    float w[4];
};

// Geometry for one position -> clamped corner offsets + mask-folded weights.
__device__ inline void make_geo(const float* pts, int pos, int wp, int W, int H,
                                int* soff, float* swt)
{
    const int i = pos / wp, j = pos % wp;

    float u = ((j + 0.5f) / (float)wp) * 6.0f;   // n-1 = 6
    int   i0 = (int)floorf(u);
    i0 = min(max(i0, 0), 5);
    float f = u - (float)i0;

    float txa = pts[2 * i0]     / 1344.0f, tya = pts[2 * i0 + 1] / 800.0f;
    float txb = pts[2 * i0 + 2] / 1344.0f, tyb = pts[2 * i0 + 3] / 800.0f;
    int ka = 13 - i0, kb = 12 - i0;               // bottom points reversed
    float bxa = pts[2 * ka] / 1344.0f, bya = pts[2 * ka + 1] / 800.0f;
    float bxb = pts[2 * kb] / 1344.0f, byb = pts[2 * kb + 1] / 800.0f;

    float topx = txa * (1.0f - f) + txb * f;
    float topy = tya * (1.0f - f) + tyb * f;
    float botx = bxa * (1.0f - f) + bxb * f;
    float boty = bya * (1.0f - f) + byb * f;

    float v  = (i + 0.5f) / 8.0f;
    float gx = topx * (1.0f - v) + botx * v;
    float gy = topy * (1.0f - v) + boty * v;

    float x = gx * (float)W - 0.5f;
    float y = gy * (float)H - 0.5f;
    float x0f = floorf(x), y0f = floorf(y);
    float fx = x - x0f,   fy = y - y0f;
    int x0 = (int)x0f, y0 = (int)y0f;
    int x1 = x0 + 1,   y1 = y0 + 1;

    int x0c = min(max(x0, 0), W - 1), x1c = min(max(x1, 0), W - 1);
    int y0c = min(max(y0, 0), H - 1), y1c = min(max(y1, 0), H - 1);
    float m00 = (x0 >= 0 && x0 < W && y0 >= 0 && y0 < H) ? 1.0f : 0.0f;
    float m10 = (x1 >= 0 && x1 < W && y0 >= 0 && y0 < H) ? 1.0f : 0.0f;
    float m01 = (x0 >= 0 && x0 < W && y1 >= 0 && y1 < H) ? 1.0f : 0.0f;
    float m11 = (x1 >= 0 && x1 < W && y1 >= 0 && y1 < H) ? 1.0f : 0.0f;

    soff[0] = y0c * W + x0c;
    soff[1] = y0c * W + x1c;
    soff[2] = y1c * W + x0c;
    soff[3] = y1c * W + x1c;
    swt[0] = (1.0f - fx) * (1.0f - fy) * m00;
    swt[1] = fx * (1.0f - fy) * m10;
    swt[2] = (1.0f - fx) * fy * m01;
    swt[3] = fx * fy * m11;
}

// WP: output width; PPT: positions per thread (WP*8/256); UNROLL: channels/iter.
template <int WP, int PPT, int UNROLL>
__device__ inline void pool_body(const float* __restrict__ featimg, int W, int H,
                                 const float* pts, float* __restrict__ outb, int c0,
                                 int tid)
{
    constexpr int NPOS = HP * WP;
    __shared__ int   soff[NPOS][4];
    __shared__ float swt [NPOS][4];

    for (int pos = tid; pos < NPOS; pos += 256)
        make_geo(pts, pos, WP, W, H, &soff[pos][0], &swt[pos][0]);
    __syncthreads();

    // thread owns PPT ADJACENT positions: p = tid*PPT + {0..PPT-1}
    Geo g[PPT];
#pragma unroll
    for (int p = 0; p < PPT; ++p) {
        const int pos = tid * PPT + p;
#pragma unroll
        for (int k = 0; k < 4; ++k) { g[p].o[k] = soff[pos][k]; g[p].w[k] = swt[pos][k]; }
    }

    const size_t HWs = (size_t)H * W;
    for (int cc = 0; cc < CCHUNK; cc += UNROLL) {
        float v[UNROLL][PPT][4];
#pragma unroll
        for (int u = 0; u < UNROLL; ++u) {
            const float* fc = featimg + (size_t)(c0 + cc + u) * HWs;
#pragma unroll
            for (int p = 0; p < PPT; ++p)
#pragma unroll
                for (int k = 0; k < 4; ++k)
                    v[u][p][k] = fc[g[p].o[k]];
        }
#pragma unroll
        for (int u = 0; u < UNROLL; ++u) {
            float r[PPT];
#pragma unroll
            for (int p = 0; p < PPT; ++p)
                r[p] = g[p].w[0] * v[u][p][0] + g[p].w[1] * v[u][p][1]
                     + g[p].w[2] * v[u][p][2] + g[p].w[3] * v[u][p][3];
            float* dst = outb + (size_t)(c0 + cc + u) * NPOS + tid * PPT;
            if (PPT == 2) {
                *(float2*)dst = make_float2(r[0], r[PPT - 1]);
            } else {
                dst[0] = r[0];
            }
        }
    }
}

__global__ __launch_bounds__(256) void poly_pool_kernel(
    const float* __restrict__ f0, const float* __restrict__ f1,
    const float* __restrict__ f2, const float* __restrict__ f3,
    const float* __restrict__ polys, const int* __restrict__ img_ids,
    const int* __restrict__ lens, float* __restrict__ out)
{
    const int b    = blockIdx.y;
    const int pidk = blockIdx.z;            // 0 -> (8,32), 1 -> (8,64)
    const int npos = pidk ? 512 : 256;
    const int c0   = blockIdx.x * CCHUNK;
    const int tid  = threadIdx.x;

    float* outb = out + (pidk ? OUT0_ELEMS : 0) + (size_t)b * NCH * npos;

    // pooler routing: pooler_id = (lens > 8)
    const int pooler = (lens[b] > 8) ? 1 : 0;
    if (pooler != pidk) {
        // this box contributes zeros to this output tensor (float4 fill)
        float4* p = (float4*)(outb + (size_t)c0 * npos);
        const int total4 = (CCHUNK * npos) / 4;
        const float4 z = make_float4(0.f, 0.f, 0.f, 0.f);
        for (int k = tid; k < total4; k += 256) p[k] = z;
        return;
    }

    __shared__ float pts[28];
    if (tid < 28) pts[tid] = polys[b * 28 + tid];
    __syncthreads();

    // ---- level selection: s = sqrt(dx*dy) over raw points ----
    float minx = pts[0], maxx = pts[0], miny = pts[1], maxy = pts[1];
#pragma unroll
    for (int k = 1; k < 14; ++k) {
        float x = pts[2 * k], y = pts[2 * k + 1];
        minx = fminf(minx, x); maxx = fmaxf(maxx, x);
        miny = fminf(miny, y); maxy = fmaxf(maxy, y);
    }
    float s = sqrtf((maxx - minx) * (maxy - miny));
    int lvl = (int)floorf(4.0f + log2f(s / 224.0f + 1e-6f));
    lvl = min(max(lvl, 2), 5) - 2;

    const float* feat; int H, W;
    switch (lvl) {
        case 0:  feat = f0; H = 200; W = 336; break;
        case 1:  feat = f1; H = 100; W = 168; break;
        case 2:  feat = f2; H = 50;  W = 84;  break;
        default: feat = f3; H = 25;  W = 42;  break;
    }
    const float* featimg = feat + (size_t)img_ids[b] * NCH * H * W;

    if (pidk == 0) pool_body<32, 1, 8>(featimg, W, H, pts, outb, c0, tid);
    else           pool_body<64, 2, 4>(featimg, W, H, pts, outb, c0, tid);
}

extern "C" void kernel_launch(void* const* d_in, const int* in_sizes, int n_in,
                              void* d_out, int out_size, void* d_ws, size_t ws_size,
                              hipStream_t stream) {
    const float* f0    = (const float*)d_in[0];
    const float* f1    = (const float*)d_in[1];
    const float* f2    = (const float*)d_in[2];
    const float* f3    = (const float*)d_in[3];
    const float* polys = (const float*)d_in[4];
    const int*   ids   = (const int*)d_in[5];
    const int*   lens  = (const int*)d_in[6];
    float* out = (float*)d_out;

    dim3 grid(NCH / CCHUNK, NBOX, 2);   // (8, 256, 2)
    poly_pool_kernel<<<grid, 256, 0, stream>>>(f0, f1, f2, f3, polys, ids, lens, out);
}

// Round 4
// 370.768 us; speedup vs baseline: 1.0165x; 1.0165x over previous
//
#include <hip/hip_runtime.h>

// PolyPoolerTextLenSensitive — MI355X (gfx950)
//
// R4 = R3 with compile fix: __builtin_nontemporal_store needs clang
// ext_vector_type, not HIP_vector_type (float2/float4).
//
// R3 design:
//  - single unioned LDS geometry block (16.5 KB, was 25 KB double-alloc)
//  - explicit load-batch / consume phases separated by sched_barrier(0)
//    so the compiler cannot re-interleave load->use (R2: VGPR=44 proved
//    it had serialized the gathers)
//  - __launch_bounds__(256,4): >=4 blocks/CU, VGPR<=128
//  - nontemporal output stores (201 MB stream, never re-read by us)

#define NBOX 256
#define NCH  256
#define HP   8
#define CCHUNK 32
#define OUT0_ELEMS ((size_t)NBOX * NCH * HP * 32)

typedef float f32x2 __attribute__((ext_vector_type(2)));
typedef float f32x4 __attribute__((ext_vector_type(4)));

// Geometry for one position -> clamped corner offsets + mask-folded weights.
__device__ inline void make_geo(const float* pts, int pos, int wp, int W, int H,
                                int* soff, float* swt)
{
    const int i = pos / wp, j = pos % wp;

    float u = ((j + 0.5f) / (float)wp) * 6.0f;   // n-1 = 6
    int   i0 = (int)floorf(u);
    i0 = min(max(i0, 0), 5);
    float f = u - (float)i0;

    float txa = pts[2 * i0]     / 1344.0f, tya = pts[2 * i0 + 1] / 800.0f;
    float txb = pts[2 * i0 + 2] / 1344.0f, tyb = pts[2 * i0 + 3] / 800.0f;
    int ka = 13 - i0, kb = 12 - i0;               // bottom points reversed
    float bxa = pts[2 * ka] / 1344.0f, bya = pts[2 * ka + 1] / 800.0f;
    float bxb = pts[2 * kb] / 1344.0f, byb = pts[2 * kb + 1] / 800.0f;

    float topx = txa * (1.0f - f) + txb * f;
    float topy = tya * (1.0f - f) + tyb * f;
    float botx = bxa * (1.0f - f) + bxb * f;
    float boty = bya * (1.0f - f) + byb * f;

    float v  = (i + 0.5f) / 8.0f;
    float gx = topx * (1.0f - v) + botx * v;
    float gy = topy * (1.0f - v) + boty * v;

    float x = gx * (float)W - 0.5f;
    float y = gy * (float)H - 0.5f;
    float x0f = floorf(x), y0f = floorf(y);
    float fx = x - x0f,   fy = y - y0f;
    int x0 = (int)x0f, y0 = (int)y0f;
    int x1 = x0 + 1,   y1 = y0 + 1;

    int x0c = min(max(x0, 0), W - 1), x1c = min(max(x1, 0), W - 1);
    int y0c = min(max(y0, 0), H - 1), y1c = min(max(y1, 0), H - 1);
    float m00 = (x0 >= 0 && x0 < W && y0 >= 0 && y0 < H) ? 1.0f : 0.0f;
    float m10 = (x1 >= 0 && x1 < W && y0 >= 0 && y0 < H) ? 1.0f : 0.0f;
    float m01 = (x0 >= 0 && x0 < W && y1 >= 0 && y1 < H) ? 1.0f : 0.0f;
    float m11 = (x1 >= 0 && x1 < W && y1 >= 0 && y1 < H) ? 1.0f : 0.0f;

    soff[0] = y0c * W + x0c;
    soff[1] = y0c * W + x1c;
    soff[2] = y1c * W + x0c;
    soff[3] = y1c * W + x1c;
    swt[0] = (1.0f - fx) * (1.0f - fy) * m00;
    swt[1] = fx * (1.0f - fy) * m10;
    swt[2] = (1.0f - fx) * fy * m01;
    swt[3] = fx * fy * m11;
}

// PPT: positions per thread; UNROLL: channels per batch. UNROLL*PPT*4 = 32
// gathers issued back-to-back before any use.
template <int PPT, int UNROLL>
__device__ inline void pool_body(const float* __restrict__ featimg, size_t HW,
                                 float* __restrict__ outb, int c0, int tid,
                                 const int (*soff)[4], const float (*swt)[4])
{
    constexpr int NPOS = 256 * PPT;

    int   o[PPT][4];
    float w[PPT][4];
#pragma unroll
    for (int p = 0; p < PPT; ++p) {
        const int pos = tid * PPT + p;
#pragma unroll
        for (int k = 0; k < 4; ++k) { o[p][k] = soff[pos][k]; w[p][k] = swt[pos][k]; }
    }

    for (int cc = 0; cc < CCHUNK; cc += UNROLL) {
        float v[UNROLL][PPT][4];
        const float* fb = featimg + (size_t)(c0 + cc) * HW;
#pragma unroll
        for (int u = 0; u < UNROLL; ++u)
#pragma unroll
            for (int p = 0; p < PPT; ++p)
#pragma unroll
                for (int k = 0; k < 4; ++k)
                    v[u][p][k] = fb[(size_t)u * HW + o[p][k]];

        // Keep all 32 loads in flight: nothing may cross this point.
        __builtin_amdgcn_sched_barrier(0);

#pragma unroll
        for (int u = 0; u < UNROLL; ++u) {
            float r[PPT];
#pragma unroll
            for (int p = 0; p < PPT; ++p)
                r[p] = w[p][0] * v[u][p][0] + w[p][1] * v[u][p][1]
                     + w[p][2] * v[u][p][2] + w[p][3] * v[u][p][3];
            float* dst = outb + (size_t)(c0 + cc + u) * NPOS + tid * PPT;
            if (PPT == 2) {
                f32x2 rv = { r[0], r[PPT - 1] };
                __builtin_nontemporal_store(rv, (f32x2*)dst);
            } else {
                __builtin_nontemporal_store(r[0], dst);
            }
        }
    }
}

__global__ __launch_bounds__(256, 4) void poly_pool_kernel(
    const float* __restrict__ f0, const float* __restrict__ f1,
    const float* __restrict__ f2, const float* __restrict__ f3,
    const float* __restrict__ polys, const int* __restrict__ img_ids,
    const int* __restrict__ lens, float* __restrict__ out)
{
    const int b    = blockIdx.y;
    const int pidk = blockIdx.z;            // 0 -> (8,32), 1 -> (8,64)
    const int wp   = pidk ? 64 : 32;
    const int npos = HP * wp;
    const int c0   = blockIdx.x * CCHUNK;
    const int tid  = threadIdx.x;

    float* outb = out + (pidk ? OUT0_ELEMS : 0) + (size_t)b * NCH * npos;

    // pooler routing: pooler_id = (lens > 8)
    const int pooler = (lens[b] > 8) ? 1 : 0;
    if (pooler != pidk) {
        // this box contributes zeros to this output tensor (16B fill)
        f32x4* p = (f32x4*)(outb + (size_t)c0 * npos);
        const int total4 = (CCHUNK * npos) / 4;
        const f32x4 z = { 0.f, 0.f, 0.f, 0.f };
        for (int k = tid; k < total4; k += 256)
            __builtin_nontemporal_store(z, &p[k]);
        return;
    }

    // ---- unioned LDS: one geometry block for both paths (16.5 KB) ----
    __shared__ float pts[28];
    __shared__ int   soff[512][4];
    __shared__ float swt [512][4];

    if (tid < 28) pts[tid] = polys[b * 28 + tid];
    __syncthreads();

    // ---- level selection: s = sqrt(dx*dy) over raw points ----
    float minx = pts[0], maxx = pts[0], miny = pts[1], maxy = pts[1];
#pragma unroll
    for (int k = 1; k < 14; ++k) {
        float x = pts[2 * k], y = pts[2 * k + 1];
        minx = fminf(minx, x); maxx = fmaxf(maxx, x);
        miny = fminf(miny, y); maxy = fmaxf(maxy, y);
    }
    float s = sqrtf((maxx - minx) * (maxy - miny));
    int lvl = (int)floorf(4.0f + log2f(s / 224.0f + 1e-6f));
    lvl = min(max(lvl, 2), 5) - 2;

    const float* feat; int H, W;
    switch (lvl) {
        case 0:  feat = f0; H = 200; W = 336; break;
        case 1:  feat = f1; H = 100; W = 168; break;
        case 2:  feat = f2; H = 50;  W = 84;  break;
        default: feat = f3; H = 25;  W = 42;  break;
    }
    const float* featimg = feat + (size_t)img_ids[b] * NCH * H * W;

    for (int pos = tid; pos < npos; pos += 256)
        make_geo(pts, pos, wp, W, H, &soff[pos][0], &swt[pos][0]);
    __syncthreads();

    const size_t HW = (size_t)H * W;
    if (pidk == 0) pool_body<1, 8>(featimg, HW, outb, c0, tid, soff, swt);
    else           pool_body<2, 4>(featimg, HW, outb, c0, tid, soff, swt);
}

extern "C" void kernel_launch(void* const* d_in, const int* in_sizes, int n_in,
                              void* d_out, int out_size, void* d_ws, size_t ws_size,
                              hipStream_t stream) {
    const float* f0    = (const float*)d_in[0];
    const float* f1    = (const float*)d_in[1];
    const float* f2    = (const float*)d_in[2];
    const float* f3    = (const float*)d_in[3];
    const float* polys = (const float*)d_in[4];
    const int*   ids   = (const int*)d_in[5];
    const int*   lens  = (const int*)d_in[6];
    float* out = (float*)d_out;

    dim3 grid(NCH / CCHUNK, NBOX, 2);   // (8, 256, 2)
    poly_pool_kernel<<<grid, 256, 0, stream>>>(f0, f1, f2, f3, polys, ids, lens, out);
}